// Round 21
// baseline (97.028 us; speedup 1.0000x reference)
//
#include <hip/hip_runtime.h>

// SlayerNet SNN forward, MI355X.
// y1 = w1@x [k_mm1: 16 waves = 2 o-halves (13/12) x 8 c-groups (32,32,31x6),
//   float1/lane, acc[13], 16-float padded weight rows (1 s_load_dwordx16/ch),
//   LDS fold, 8 waves/SIMD] ;
// pot1 = FIR129(y1) [k_fir1] ; s1 = scan [bits] ;
// pot2 = FIR129(w2@s1) [linearity swap, b128 FIR] ; s2 = scan -> d_out (fp32).
// Spike scans: speculative block-parallel + exact fixup (state = last 15 spike
// bits; 15-bit mask match => bitwise-exact). Spec/fix SEPARATE kernels
// (R19: fusing layer-2 scan serializes onto one CU).

#define T_LEN   65536
#define NCH     250
#define NO1     25
#define KTAPS   129      // taps d=0..128, eps[d] = srm[128-d]
#define PAD     128
#define SRM_LEN 257
#define REF_LEN 16
#define THETA_F 10.0f
#define LBLK    64       // scan block length (== 2 x 32-bit words)
#define NBK     1024     // NBK*LBLK == T_LEN
#define WARM    64       // speculative warm-up steps
#define TT      64       // mm1 time-tile (1 position per lane)
#define FTILE   1024     // fir1 tile
#define FT2     1024     // pot2 tile
#define NWORDS  (T_LEN / 32)

// One gen_spikes step. fma(s,rn,b) is bit-exact vs fadd(b,fmul(s,rn)):
// s in {0,1} makes the product exact, so single rounding = same rounding.
__device__ __forceinline__ void srm_step(float p, const float (&rn)[15], float (&b)[15],
                                         unsigned &m, float &sf_out) {
  float u = p + b[0];
  unsigned sp = (u >= THETA_F) ? 1u : 0u;
  float sf = sp ? 1.0f : 0.0f;
#pragma unroll
  for (int j = 0; j < 14; ++j) b[j] = __builtin_fmaf(sf, rn[j], b[j + 1]);
  b[14] = __fmul_rn(sf, rn[14]);
  m = (m << 1) | sp;
  sf_out = sf;
}

__global__ void k_fill(float* out, float v) {
  out[blockIdx.x * 256 + threadIdx.x] = v;
}

// Padded per-half weights: wg3[oh][c][j] = w1[oh*13+j][c] (j < no(oh)) else 0.
// 16 floats per channel, 64B-aligned -> one s_load_dwordx16 per channel.
__global__ __launch_bounds__(256) void k_prep4(const float* __restrict__ w1,
                                               float* __restrict__ wg3) {
  for (int i = threadIdx.x; i < 2 * NCH * 16; i += 256) {
    int oh = i / (NCH * 16);
    int r = i - oh * (NCH * 16);
    int c = r >> 4;
    int j = r & 15;
    int ob = oh * 13;
    int no = oh ? 12 : 13;
    wg3[i] = (j < no) ? w1[(ob + j) * NCH + c] : 0.0f;
  }
}

template <int CN>
__device__ __forceinline__ void mm_body8(const float* __restrict__ xp,
                                         const float* __restrict__ wp,
                                         float (&acc)[13]) {
#pragma unroll 8
  for (int c = 0; c < CN; ++c) {
    float xv = xp[(size_t)c * T_LEN];       // 256B/wave coalesced
    const float* wr = wp + c * 16;          // uniform, 64B-aligned -> dwordx16
#pragma unroll
    for (int j = 0; j < 13; ++j)            // j==12 zero-weight for oh==1
      acc[j] = __builtin_fmaf(wr[j], xv, acc[j]);
  }
}

// K1: y1[o][t] = sum_{c} w1[o][c]*x[c][t].
// 1024 thr = 16 waves: wave w -> o-half (w&1), c-group (w>>1) of
// (32,32,31,31,31,31,31,31). x traffic = 2x (vs 4x in o-quad split).
// Fold 8 groups left-to-right via LDS (ascending-c association).
__global__ __launch_bounds__(1024, 8) void k_mm1(const float* __restrict__ x,
                                                 const float* __restrict__ wg3,
                                                 float* __restrict__ y1) {
  __shared__ __align__(16) float part[7][2][13][64];  // 46592 B (cg=1..7)
  const int tid = threadIdx.x;
  const int lane = tid & 63;
  const int w = __builtin_amdgcn_readfirstlane(tid >> 6);  // 0..15
  const int oh = w & 1;
  const int cg = w >> 1;   // 0..7
  const int ob = oh * 13;
  const int no = oh ? 12 : 13;
  const int cs = (cg < 2) ? cg * 32 : 64 + (cg - 2) * 31;
  const int t = blockIdx.x * TT + lane;
  const float* wp = wg3 + oh * (NCH * 16) + cs * 16;  // SGPR base
  const float* xp = x + (size_t)cs * T_LEN + t;
  float acc[13];
#pragma unroll
  for (int j = 0; j < 13; ++j) acc[j] = 0.f;
  if (cg < 2) mm_body8<32>(xp, wp, acc);
  else        mm_body8<31>(xp, wp, acc);
  if (cg > 0) {
#pragma unroll
    for (int j = 0; j < 13; ++j) part[cg - 1][oh][j][lane] = acc[j];
  }
  __syncthreads();
  if (cg == 0) {
#pragma unroll
    for (int j = 0; j < 13; ++j) {
      float a = acc[j];
#pragma unroll
      for (int g = 0; g < 7; ++g) a = __fadd_rn(a, part[g][oh][j][lane]);
      if (j < no) y1[(size_t)(ob + j) * T_LEN + t] = a;
    }
  }
}

// K2: pot1[o][t] = sum_d eps[d]*y1[o][t-d]; plain y1 layout.
__global__ __launch_bounds__(256, 8) void k_fir1(const float* __restrict__ y1,
                                                 const float* __restrict__ srm,
                                                 float* __restrict__ pot1) {
  __shared__ __align__(16) float win[FTILE + PAD];
  const int tid = threadIdx.x;
  const int o = blockIdx.y;
  const int t0 = blockIdx.x * FTILE;
  const float* yr = y1 + (size_t)o * T_LEN;
  for (int j = tid; j < FTILE + PAD; j += 256) {
    int g = t0 - PAD + j;
    win[j] = (g >= 0) ? yr[g] : 0.0f;
  }
  __syncthreads();
  const int base = tid * 4;
  float q0 = 0.0f, q1 = 0.0f, q2 = 0.0f, q3 = 0.0f;
  // i descending => per-output tap order d ascending (proven ordering).
#pragma unroll
  for (int i = 32; i >= 0; --i) {
    float4 v = *(const float4*)&win[base + 4 * i];
#pragma unroll
    for (int l = 3; l >= 0; --l) {
      float vl = (l == 0) ? v.x : (l == 1) ? v.y : (l == 2) ? v.z : v.w;
#pragma unroll
      for (int k = 0; k < 4; ++k) {
        int d = 128 + k - 4 * i - l;
        if (d >= 0 && d <= 128) {
          float e = srm[4 * i + l - k];  // uniform -> scalar load
          if (k == 0) q0 = __builtin_fmaf(e, vl, q0);
          else if (k == 1) q1 = __builtin_fmaf(e, vl, q1);
          else if (k == 2) q2 = __builtin_fmaf(e, vl, q2);
          else q3 = __builtin_fmaf(e, vl, q3);
        }
      }
    }
  }
  *(float4*)&pot1[(size_t)o * T_LEN + t0 + base] = make_float4(q0, q1, q2, q3);
}

// K5: pot2 = FIR129( z ),  z[t] = sum_o w2[o] * s1[o][t]  (bit-packed s1).
__global__ __launch_bounds__(256) void k_pot2(const unsigned* __restrict__ s1p,
                                              const float* __restrict__ srm,
                                              const float* __restrict__ w2,
                                              float* __restrict__ pot2) {
  __shared__ __align__(16) float zs[FT2 + PAD];
  const int tid = threadIdx.x;
  const int t0 = blockIdx.x * FT2;
  for (int j = tid; j < FT2 + PAD; j += 256) {
    int g = t0 - PAD + j;
    float z = 0.0f;
    if (g >= 0) {
      int wi = g >> 5, sh = g & 31;
#pragma unroll
      for (int o = 0; o < NO1; ++o) {
        unsigned wvv = s1p[o * NWORDS + wi];
        z += ((wvv >> sh) & 1u) ? w2[o] : 0.0f;  // w2: uniform scalar load
      }
    }
    zs[j] = z;
  }
  __syncthreads();
  const int base = tid * 4;
  float q0 = 0.0f, q1 = 0.0f, q2 = 0.0f, q3 = 0.0f;
#pragma unroll
  for (int i = 32; i >= 0; --i) {
    float4 v = *(const float4*)&zs[base + 4 * i];
#pragma unroll
    for (int l = 3; l >= 0; --l) {
      float vl = (l == 0) ? v.x : (l == 1) ? v.y : (l == 2) ? v.z : v.w;
#pragma unroll
      for (int k = 0; k < 4; ++k) {
        int d = 128 + k - 4 * i - l;
        if (d >= 0 && d <= 128) {
          float e = srm[4 * i + l - k];
          if (k == 0) q0 = __builtin_fmaf(e, vl, q0);
          else if (k == 1) q1 = __builtin_fmaf(e, vl, q1);
          else if (k == 2) q2 = __builtin_fmaf(e, vl, q2);
          else q3 = __builtin_fmaf(e, vl, q3);
        }
      }
    }
  }
  *(float4*)&pot2[t0 + base] = make_float4(q0, q1, q2, q3);
}

// Speculative scan: one thread per (channel, block). WARM steps from assumed
// zero state, then LBLK emitted steps; 4-deep float4 prefetch (16 steps/iter).
template <int C, bool PACKED>
__global__ __launch_bounds__(64) void k_scan_spec(const float* __restrict__ pot,
                                                  const float* __restrict__ refk,
                                                  float* __restrict__ s,
                                                  unsigned* __restrict__ sp_,
                                                  unsigned* __restrict__ specin_m,
                                                  unsigned* __restrict__ specout_m,
                                                  float* __restrict__ specout_b) {
  int idx = blockIdx.x * 64 + threadIdx.x;
  if (idx >= C * NBK) return;
  int c = idx / NBK;
  int bb = idx - c * NBK;
  int tsr = bb * LBLK - WARM;
  float rn[15];
#pragma unroll
  for (int j = 0; j < 15; ++j) rn[j] = refk[j + 1];
  float b[15];
#pragma unroll
  for (int j = 0; j < 15; ++j) b[j] = 0.0f;
  unsigned m = 0;
  const float* prow = pot + (size_t)c * T_LEN;
  float* srow = PACKED ? nullptr : (s + (size_t)c * T_LEN);
  unsigned* srowp = PACKED ? (sp_ + (size_t)c * NWORDS) : nullptr;

  auto proc4 = [&](float4 pv, int tg, bool emit) {
    float s0, s1v, s2, s3;
    srm_step(pv.x, rn, b, m, s0);
    srm_step(pv.y, rn, b, m, s1v);
    srm_step(pv.z, rn, b, m, s2);
    srm_step(pv.w, rn, b, m, s3);
    if (emit) {
      if (PACKED) {
        if (((tg + 3) & 31) == 31) srowp[(tg - 28) >> 5] = __brev(m);
      } else {
        *(float4*)(srow + tg) = make_float4(s0, s1v, s2, s3);
      }
    }
  };

  for (int k = 0; k < WARM + LBLK; k += 16) {
    if (k == WARM) specin_m[idx] = m & 0x7FFFu;
    int t = tsr + k;
    if (t < 0) continue;   // t is a multiple of 16; never partially negative
    float4 p0 = *(const float4*)(prow + t);
    float4 p1 = *(const float4*)(prow + t + 4);
    float4 p2 = *(const float4*)(prow + t + 8);
    float4 p3 = *(const float4*)(prow + t + 12);
    const bool emit = (k >= WARM);
    proc4(p0, t, emit);
    proc4(p1, t + 4, emit);
    proc4(p2, t + 8, emit);
    proc4(p3, t + 12, emit);
  }
  specout_m[idx] = m & 0x7FFFu;
#pragma unroll
  for (int j = 0; j < 15; ++j) specout_b[idx * 16 + j] = b[j];
}

// Exact fixup: one WAVE per channel. All 16 mask-groups preloaded, ballot
// chain check => 64 blocks/iter fast path; mismatch path walks via shuffles.
template <int C, bool PACKED>
__global__ __launch_bounds__(64) void k_scan_fix(const float* __restrict__ pot,
                                                 const float* __restrict__ refk,
                                                 float* __restrict__ s,
                                                 unsigned* __restrict__ sp_,
                                                 const unsigned* __restrict__ specin_m,
                                                 const unsigned* __restrict__ specout_m,
                                                 const float* __restrict__ specout_b) {
  const int c = blockIdx.x;
  const int lane = threadIdx.x;
  float rn[15];
#pragma unroll
  for (int j = 0; j < 15; ++j) rn[j] = refk[j + 1];
  float b[15];
#pragma unroll
  for (int j = 0; j < 15; ++j) b[j] = 0.0f;
  unsigned m = 0;
  bool haveB = true;
  const float* prow = pot + (size_t)c * T_LEN;
  float* srow = PACKED ? nullptr : (s + (size_t)c * T_LEN);
  unsigned* srowp = PACKED ? (sp_ + (size_t)c * NWORDS) : nullptr;
  unsigned prev_last = 0;

  unsigned siv[NBK / 64], sov[NBK / 64];
#pragma unroll
  for (int g = 0; g < NBK / 64; ++g) {
    siv[g] = specin_m[c * NBK + g * 64 + lane];
    sov[g] = specout_m[c * NBK + g * 64 + lane];
  }
#pragma unroll
  for (int g = 0; g < NBK / 64; ++g) {
    const unsigned si = siv[g];
    const unsigned so = sov[g];
    unsigned so_prev = __shfl_up(so, 1);
    if (lane == 0) so_prev = prev_last;
    const unsigned long long flags = __ballot(si == so_prev);
    prev_last = __shfl(so, 63);
    const unsigned si0 = __shfl(si, 0);
    if (flags == ~0ull && (m & 0x7FFFu) == si0) {
      m = prev_last;
      haveB = false;
      continue;
    }
    for (int r = 0; r < 64; ++r) {
      const unsigned sir = __shfl(si, r);
      const unsigned sor = __shfl(so, r);
      if ((m & 0x7FFFu) == sir) {
        m = sor;
        haveB = false;
      } else {
        const int bbr = g * 64 + r;  // bbr>=1: block 0 entry mask 0 always matches
        if (!haveB) {
          const int pb = (c * NBK + bbr - 1) * 16;
#pragma unroll
          for (int q2 = 0; q2 < 15; ++q2) b[q2] = specout_b[pb + q2];
          haveB = true;
        }
        const int t0 = bbr * LBLK;
        for (int t = t0; t < t0 + LBLK; t += 4) {
          float4 pv = *(const float4*)(prow + t);
          float s0, s1v, s2, s3;
          srm_step(pv.x, rn, b, m, s0);
          srm_step(pv.y, rn, b, m, s1v);
          srm_step(pv.z, rn, b, m, s2);
          srm_step(pv.w, rn, b, m, s3);
          if (PACKED) {
            if ((((t + 3) & 31) == 31) && lane == 0) srowp[(t - 28) >> 5] = __brev(m);
          } else {
            if (lane == 0) *(float4*)(srow + t) = make_float4(s0, s1v, s2, s3);
          }
        }
        haveB = true;
      }
    }
  }
}

extern "C" void kernel_launch(void* const* d_in, const int* in_sizes, int n_in,
                              void* d_out, int out_size, void* d_ws, size_t ws_size,
                              hipStream_t stream) {
  const float* x    = (const float*)d_in[0];  // 250*65536
  const float* srm  = (const float*)d_in[1];  // 257
  const float* refk = (const float*)d_in[2];  // 16
  const float* w1   = (const float*)d_in[3];  // 25*250
  const float* w2   = (const float*)d_in[4];  // 25
  float* out = (float*)d_out;

  float bad = 0.0f;
  if (n_in != 5) bad = 3.0f;
  else if (in_sizes[0] != NCH * T_LEN) bad = 4.0f;
  else if (in_sizes[1] != SRM_LEN)     bad = 5.0f;
  else if (in_sizes[2] != REF_LEN)     bad = 6.0f;
  else if (in_sizes[3] != NO1 * NCH)   bad = 7.0f;
  else if (in_sizes[4] != NO1)         bad = 8.0f;
  else if (out_size != T_LEN)          bad = 9.0f;
  if (bad != 0.0f) {
    k_fill<<<T_LEN / 256, 256, 0, stream>>>(out, bad);
    return;
  }

  size_t off = 0;
  auto alloc = [&](size_t bytes) { size_t o = off; off = (off + bytes + 255) & ~(size_t)255; return o; };
  char* ws = (char*)d_ws;
  size_t oY1  = alloc((size_t)NO1 * T_LEN * 4);        // 6.55 MB (dead after k_fir1)
  size_t oP1  = alloc((size_t)NO1 * T_LEN * 4);        // 6.55 MB
  size_t oS1P = alloc((size_t)NO1 * NWORDS * 4);       // 205 KB
  size_t oP2  = alloc((size_t)T_LEN * 4);              // 262 KB
  size_t oWG3 = alloc((size_t)2 * NCH * 16 * 4);       // 32 KB
  if (ws_size < off) {
    k_fill<<<T_LEN / 256, 256, 0, stream>>>(out, 2.0f);
    return;
  }

  float*    y1   = (float*)(ws + oY1);
  float*    pot1 = (float*)(ws + oP1);
  unsigned* s1p  = (unsigned*)(ws + oS1P);
  float*    pot2 = (float*)(ws + oP2);
  float*    wg3  = (float*)(ws + oWG3);
  // spec buffers alias the y1 region (dead once k_fir1 completes; spec
  // kernels launch after k_fir1 in stream order). Offsets 256-aligned.
  char* yb = ws + oY1;
  unsigned* si1 = (unsigned*)(yb);                  // 25*1024*4 = 102400 B
  unsigned* so1 = (unsigned*)(yb + 102400);         // 102400 B
  float*    sb1 = (float*)   (yb + 204800);         // 25*1024*64 = 1638400 B
  unsigned* si2 = (unsigned*)(yb + 1843200);        // 4096 B
  unsigned* so2 = (unsigned*)(yb + 1847296);        // 4096 B
  float*    sb2 = (float*)   (yb + 1851392);        // 65536 B

  k_prep4<<<1, 256, 0, stream>>>(w1, wg3);
  k_mm1<<<T_LEN / TT, 1024, 0, stream>>>(x, wg3, y1);
  k_fir1<<<dim3(T_LEN / FTILE, NO1), 256, 0, stream>>>(y1, srm, pot1);
  k_scan_spec<NO1, true><<<(NO1 * NBK + 63) / 64, 64, 0, stream>>>(
      pot1, refk, nullptr, s1p, si1, so1, sb1);
  k_scan_fix<NO1, true><<<NO1, 64, 0, stream>>>(pot1, refk, nullptr, s1p, si1, so1, sb1);
  k_pot2<<<T_LEN / FT2, 256, 0, stream>>>(s1p, srm, w2, pot2);
  k_scan_spec<1, false><<<(NBK + 63) / 64, 64, 0, stream>>>(
      pot2, refk, out, nullptr, si2, so2, sb2);
  k_scan_fix<1, false><<<1, 64, 0, stream>>>(pot2, refk, out, nullptr, si2, so2, sb2);
}

// Round 22
// 92.747 us; speedup vs baseline: 1.0462x; 1.0462x over previous
//
#include <hip/hip_runtime.h>

// SlayerNet SNN forward, MI355X.
// y1 = w1@x [k_mm1: 16 waves = 2 o-halves (13/12) x 8 c-groups (32,32,31x6),
//   float1/lane, acc[13], weights staged in LDS (wave-uniform broadcast
//   ds_read -- bypasses the 16KB scalar cache that serialized s_load variants),
//   LDS fold, 8 waves/SIMD] ;
// pot1 = FIR129(y1) [k_fir1] ; s1 = scan [bits] ;
// pot2 = FIR129(w2@s1) [linearity swap, b128 FIR] ; s2 = scan -> d_out (fp32).
// Spike scans: speculative block-parallel + exact fixup (state = last 15 spike
// bits; 15-bit mask match => bitwise-exact). Spec/fix SEPARATE kernels
// (R19: fusing layer-2 scan serializes onto one CU).

#define T_LEN   65536
#define NCH     250
#define NO1     25
#define KTAPS   129      // taps d=0..128, eps[d] = srm[128-d]
#define PAD     128
#define SRM_LEN 257
#define REF_LEN 16
#define THETA_F 10.0f
#define LBLK    64       // scan block length (== 2 x 32-bit words)
#define NBK     1024     // NBK*LBLK == T_LEN
#define WARM    64       // speculative warm-up steps
#define TT      64       // mm1 time-tile (1 position per lane)
#define FTILE   1024     // fir1 tile
#define FT2     1024     // pot2 tile
#define NWORDS  (T_LEN / 32)

// One gen_spikes step. fma(s,rn,b) is bit-exact vs fadd(b,fmul(s,rn)):
// s in {0,1} makes the product exact, so single rounding = same rounding.
__device__ __forceinline__ void srm_step(float p, const float (&rn)[15], float (&b)[15],
                                         unsigned &m, float &sf_out) {
  float u = p + b[0];
  unsigned sp = (u >= THETA_F) ? 1u : 0u;
  float sf = sp ? 1.0f : 0.0f;
#pragma unroll
  for (int j = 0; j < 14; ++j) b[j] = __builtin_fmaf(sf, rn[j], b[j + 1]);
  b[14] = __fmul_rn(sf, rn[14]);
  m = (m << 1) | sp;
  sf_out = sf;
}

__global__ void k_fill(float* out, float v) {
  out[blockIdx.x * 256 + threadIdx.x] = v;
}

// Padded per-half weights: wg3[oh][c][j] = w1[oh*13+j][c] (j < no(oh)) else 0.
// 16 floats per channel, 64B-aligned.
__global__ __launch_bounds__(256) void k_prep4(const float* __restrict__ w1,
                                               float* __restrict__ wg3) {
  for (int i = threadIdx.x; i < 2 * NCH * 16; i += 256) {
    int oh = i / (NCH * 16);
    int r = i - oh * (NCH * 16);
    int c = r >> 4;
    int j = r & 15;
    int ob = oh * 13;
    int no = oh ? 12 : 13;
    wg3[i] = (j < no) ? w1[(ob + j) * NCH + c] : 0.0f;
  }
}

// K1: y1[o][t] = sum_{c} w1[o][c]*x[c][t].
// 1024 thr = 16 waves: wave w -> o-half (w&1), c-group (w>>1) of
// (32,32,31,31,31,31,31,31). Weights from LDS (uniform broadcast, conflict-
// free, compiler-pipelined lgkmcnt). Fold 8 groups left-to-right via LDS.
__global__ __launch_bounds__(1024, 8) void k_mm1(const float* __restrict__ x,
                                                 const float* __restrict__ wg3,
                                                 float* __restrict__ y1) {
  __shared__ __align__(16) float wl[2 * NCH * 16];    // 32000 B
  __shared__ __align__(16) float part[7][2][13][64];  // 46592 B (cg=1..7)
  const int tid = threadIdx.x;
  const int lane = tid & 63;
  const int w = __builtin_amdgcn_readfirstlane(tid >> 6);  // 0..15
  const int oh = w & 1;
  const int cg = w >> 1;   // 0..7
  const int ob = oh * 13;
  const int no = oh ? 12 : 13;
  const int cs = (cg < 2) ? cg * 32 : 64 + (cg - 2) * 31;
  const int cn = (cg < 2) ? 32 : 31;
  const int t = blockIdx.x * TT + lane;
  // stage weights -> LDS (coalesced float4: 8000 floats = 2000 float4)
  for (int j = tid * 4; j < 2 * NCH * 16; j += 1024 * 4)
    *(float4*)&wl[j] = *(const float4*)&wg3[j];
  __syncthreads();
  const float* wbase = &wl[oh * (NCH * 16) + cs * 16];  // wave-uniform
  const float* xp = x + (size_t)cs * T_LEN + t;
  float acc[13];
#pragma unroll
  for (int j = 0; j < 13; ++j) acc[j] = 0.f;
#pragma unroll 4
  for (int c = 0; c < 32; ++c) {
    if (c < cn) {
      float xv = xp[(size_t)c * T_LEN];     // 256B/wave coalesced
      const float* wr = wbase + c * 16;     // uniform -> broadcast ds_read
      float4 wa = *(const float4*)(wr);
      float4 wb = *(const float4*)(wr + 4);
      float4 wc = *(const float4*)(wr + 8);
      float wd = wr[12];
      acc[0]  = __builtin_fmaf(wa.x, xv, acc[0]);
      acc[1]  = __builtin_fmaf(wa.y, xv, acc[1]);
      acc[2]  = __builtin_fmaf(wa.z, xv, acc[2]);
      acc[3]  = __builtin_fmaf(wa.w, xv, acc[3]);
      acc[4]  = __builtin_fmaf(wb.x, xv, acc[4]);
      acc[5]  = __builtin_fmaf(wb.y, xv, acc[5]);
      acc[6]  = __builtin_fmaf(wb.z, xv, acc[6]);
      acc[7]  = __builtin_fmaf(wb.w, xv, acc[7]);
      acc[8]  = __builtin_fmaf(wc.x, xv, acc[8]);
      acc[9]  = __builtin_fmaf(wc.y, xv, acc[9]);
      acc[10] = __builtin_fmaf(wc.z, xv, acc[10]);
      acc[11] = __builtin_fmaf(wc.w, xv, acc[11]);
      acc[12] = __builtin_fmaf(wd,   xv, acc[12]);
    }
  }
  if (cg > 0) {
#pragma unroll
    for (int j = 0; j < 13; ++j) part[cg - 1][oh][j][lane] = acc[j];
  }
  __syncthreads();
  if (cg == 0) {
#pragma unroll
    for (int j = 0; j < 13; ++j) {
      float a = acc[j];
#pragma unroll
      for (int g = 0; g < 7; ++g) a = __fadd_rn(a, part[g][oh][j][lane]);
      if (j < no) y1[(size_t)(ob + j) * T_LEN + t] = a;
    }
  }
}

// K2: pot1[o][t] = sum_d eps[d]*y1[o][t-d]; plain y1 layout.
__global__ __launch_bounds__(256, 8) void k_fir1(const float* __restrict__ y1,
                                                 const float* __restrict__ srm,
                                                 float* __restrict__ pot1) {
  __shared__ __align__(16) float win[FTILE + PAD];
  const int tid = threadIdx.x;
  const int o = blockIdx.y;
  const int t0 = blockIdx.x * FTILE;
  const float* yr = y1 + (size_t)o * T_LEN;
  for (int j = tid; j < FTILE + PAD; j += 256) {
    int g = t0 - PAD + j;
    win[j] = (g >= 0) ? yr[g] : 0.0f;
  }
  __syncthreads();
  const int base = tid * 4;
  float q0 = 0.0f, q1 = 0.0f, q2 = 0.0f, q3 = 0.0f;
  // i descending => per-output tap order d ascending (proven ordering).
#pragma unroll
  for (int i = 32; i >= 0; --i) {
    float4 v = *(const float4*)&win[base + 4 * i];
#pragma unroll
    for (int l = 3; l >= 0; --l) {
      float vl = (l == 0) ? v.x : (l == 1) ? v.y : (l == 2) ? v.z : v.w;
#pragma unroll
      for (int k = 0; k < 4; ++k) {
        int d = 128 + k - 4 * i - l;
        if (d >= 0 && d <= 128) {
          float e = srm[4 * i + l - k];  // uniform -> scalar load
          if (k == 0) q0 = __builtin_fmaf(e, vl, q0);
          else if (k == 1) q1 = __builtin_fmaf(e, vl, q1);
          else if (k == 2) q2 = __builtin_fmaf(e, vl, q2);
          else q3 = __builtin_fmaf(e, vl, q3);
        }
      }
    }
  }
  *(float4*)&pot1[(size_t)o * T_LEN + t0 + base] = make_float4(q0, q1, q2, q3);
}

// K5: pot2 = FIR129( z ),  z[t] = sum_o w2[o] * s1[o][t]  (bit-packed s1).
__global__ __launch_bounds__(256) void k_pot2(const unsigned* __restrict__ s1p,
                                              const float* __restrict__ srm,
                                              const float* __restrict__ w2,
                                              float* __restrict__ pot2) {
  __shared__ __align__(16) float zs[FT2 + PAD];
  const int tid = threadIdx.x;
  const int t0 = blockIdx.x * FT2;
  for (int j = tid; j < FT2 + PAD; j += 256) {
    int g = t0 - PAD + j;
    float z = 0.0f;
    if (g >= 0) {
      int wi = g >> 5, sh = g & 31;
#pragma unroll
      for (int o = 0; o < NO1; ++o) {
        unsigned wvv = s1p[o * NWORDS + wi];
        z += ((wvv >> sh) & 1u) ? w2[o] : 0.0f;  // w2: uniform scalar load
      }
    }
    zs[j] = z;
  }
  __syncthreads();
  const int base = tid * 4;
  float q0 = 0.0f, q1 = 0.0f, q2 = 0.0f, q3 = 0.0f;
#pragma unroll
  for (int i = 32; i >= 0; --i) {
    float4 v = *(const float4*)&zs[base + 4 * i];
#pragma unroll
    for (int l = 3; l >= 0; --l) {
      float vl = (l == 0) ? v.x : (l == 1) ? v.y : (l == 2) ? v.z : v.w;
#pragma unroll
      for (int k = 0; k < 4; ++k) {
        int d = 128 + k - 4 * i - l;
        if (d >= 0 && d <= 128) {
          float e = srm[4 * i + l - k];
          if (k == 0) q0 = __builtin_fmaf(e, vl, q0);
          else if (k == 1) q1 = __builtin_fmaf(e, vl, q1);
          else if (k == 2) q2 = __builtin_fmaf(e, vl, q2);
          else q3 = __builtin_fmaf(e, vl, q3);
        }
      }
    }
  }
  *(float4*)&pot2[t0 + base] = make_float4(q0, q1, q2, q3);
}

// Speculative scan: one thread per (channel, block). WARM steps from assumed
// zero state, then LBLK emitted steps; 4-deep float4 prefetch (16 steps/iter).
template <int C, bool PACKED>
__global__ __launch_bounds__(64) void k_scan_spec(const float* __restrict__ pot,
                                                  const float* __restrict__ refk,
                                                  float* __restrict__ s,
                                                  unsigned* __restrict__ sp_,
                                                  unsigned* __restrict__ specin_m,
                                                  unsigned* __restrict__ specout_m,
                                                  float* __restrict__ specout_b) {
  int idx = blockIdx.x * 64 + threadIdx.x;
  if (idx >= C * NBK) return;
  int c = idx / NBK;
  int bb = idx - c * NBK;
  int tsr = bb * LBLK - WARM;
  float rn[15];
#pragma unroll
  for (int j = 0; j < 15; ++j) rn[j] = refk[j + 1];
  float b[15];
#pragma unroll
  for (int j = 0; j < 15; ++j) b[j] = 0.0f;
  unsigned m = 0;
  const float* prow = pot + (size_t)c * T_LEN;
  float* srow = PACKED ? nullptr : (s + (size_t)c * T_LEN);
  unsigned* srowp = PACKED ? (sp_ + (size_t)c * NWORDS) : nullptr;

  auto proc4 = [&](float4 pv, int tg, bool emit) {
    float s0, s1v, s2, s3;
    srm_step(pv.x, rn, b, m, s0);
    srm_step(pv.y, rn, b, m, s1v);
    srm_step(pv.z, rn, b, m, s2);
    srm_step(pv.w, rn, b, m, s3);
    if (emit) {
      if (PACKED) {
        if (((tg + 3) & 31) == 31) srowp[(tg - 28) >> 5] = __brev(m);
      } else {
        *(float4*)(srow + tg) = make_float4(s0, s1v, s2, s3);
      }
    }
  };

  for (int k = 0; k < WARM + LBLK; k += 16) {
    if (k == WARM) specin_m[idx] = m & 0x7FFFu;
    int t = tsr + k;
    if (t < 0) continue;   // t is a multiple of 16; never partially negative
    float4 p0 = *(const float4*)(prow + t);
    float4 p1 = *(const float4*)(prow + t + 4);
    float4 p2 = *(const float4*)(prow + t + 8);
    float4 p3 = *(const float4*)(prow + t + 12);
    const bool emit = (k >= WARM);
    proc4(p0, t, emit);
    proc4(p1, t + 4, emit);
    proc4(p2, t + 8, emit);
    proc4(p3, t + 12, emit);
  }
  specout_m[idx] = m & 0x7FFFu;
#pragma unroll
  for (int j = 0; j < 15; ++j) specout_b[idx * 16 + j] = b[j];
}

// Exact fixup: one WAVE per channel. All 16 mask-groups preloaded, ballot
// chain check => 64 blocks/iter fast path; mismatch path walks via shuffles.
template <int C, bool PACKED>
__global__ __launch_bounds__(64) void k_scan_fix(const float* __restrict__ pot,
                                                 const float* __restrict__ refk,
                                                 float* __restrict__ s,
                                                 unsigned* __restrict__ sp_,
                                                 const unsigned* __restrict__ specin_m,
                                                 const unsigned* __restrict__ specout_m,
                                                 const float* __restrict__ specout_b) {
  const int c = blockIdx.x;
  const int lane = threadIdx.x;
  float rn[15];
#pragma unroll
  for (int j = 0; j < 15; ++j) rn[j] = refk[j + 1];
  float b[15];
#pragma unroll
  for (int j = 0; j < 15; ++j) b[j] = 0.0f;
  unsigned m = 0;
  bool haveB = true;
  const float* prow = pot + (size_t)c * T_LEN;
  float* srow = PACKED ? nullptr : (s + (size_t)c * T_LEN);
  unsigned* srowp = PACKED ? (sp_ + (size_t)c * NWORDS) : nullptr;
  unsigned prev_last = 0;

  unsigned siv[NBK / 64], sov[NBK / 64];
#pragma unroll
  for (int g = 0; g < NBK / 64; ++g) {
    siv[g] = specin_m[c * NBK + g * 64 + lane];
    sov[g] = specout_m[c * NBK + g * 64 + lane];
  }
#pragma unroll
  for (int g = 0; g < NBK / 64; ++g) {
    const unsigned si = siv[g];
    const unsigned so = sov[g];
    unsigned so_prev = __shfl_up(so, 1);
    if (lane == 0) so_prev = prev_last;
    const unsigned long long flags = __ballot(si == so_prev);
    prev_last = __shfl(so, 63);
    const unsigned si0 = __shfl(si, 0);
    if (flags == ~0ull && (m & 0x7FFFu) == si0) {
      m = prev_last;
      haveB = false;
      continue;
    }
    for (int r = 0; r < 64; ++r) {
      const unsigned sir = __shfl(si, r);
      const unsigned sor = __shfl(so, r);
      if ((m & 0x7FFFu) == sir) {
        m = sor;
        haveB = false;
      } else {
        const int bbr = g * 64 + r;  // bbr>=1: block 0 entry mask 0 always matches
        if (!haveB) {
          const int pb = (c * NBK + bbr - 1) * 16;
#pragma unroll
          for (int q2 = 0; q2 < 15; ++q2) b[q2] = specout_b[pb + q2];
          haveB = true;
        }
        const int t0 = bbr * LBLK;
        for (int t = t0; t < t0 + LBLK; t += 4) {
          float4 pv = *(const float4*)(prow + t);
          float s0, s1v, s2, s3;
          srm_step(pv.x, rn, b, m, s0);
          srm_step(pv.y, rn, b, m, s1v);
          srm_step(pv.z, rn, b, m, s2);
          srm_step(pv.w, rn, b, m, s3);
          if (PACKED) {
            if ((((t + 3) & 31) == 31) && lane == 0) srowp[(t - 28) >> 5] = __brev(m);
          } else {
            if (lane == 0) *(float4*)(srow + t) = make_float4(s0, s1v, s2, s3);
          }
        }
        haveB = true;
      }
    }
  }
}

extern "C" void kernel_launch(void* const* d_in, const int* in_sizes, int n_in,
                              void* d_out, int out_size, void* d_ws, size_t ws_size,
                              hipStream_t stream) {
  const float* x    = (const float*)d_in[0];  // 250*65536
  const float* srm  = (const float*)d_in[1];  // 257
  const float* refk = (const float*)d_in[2];  // 16
  const float* w1   = (const float*)d_in[3];  // 25*250
  const float* w2   = (const float*)d_in[4];  // 25
  float* out = (float*)d_out;

  float bad = 0.0f;
  if (n_in != 5) bad = 3.0f;
  else if (in_sizes[0] != NCH * T_LEN) bad = 4.0f;
  else if (in_sizes[1] != SRM_LEN)     bad = 5.0f;
  else if (in_sizes[2] != REF_LEN)     bad = 6.0f;
  else if (in_sizes[3] != NO1 * NCH)   bad = 7.0f;
  else if (in_sizes[4] != NO1)         bad = 8.0f;
  else if (out_size != T_LEN)          bad = 9.0f;
  if (bad != 0.0f) {
    k_fill<<<T_LEN / 256, 256, 0, stream>>>(out, bad);
    return;
  }

  size_t off = 0;
  auto alloc = [&](size_t bytes) { size_t o = off; off = (off + bytes + 255) & ~(size_t)255; return o; };
  char* ws = (char*)d_ws;
  size_t oY1  = alloc((size_t)NO1 * T_LEN * 4);        // 6.55 MB (dead after k_fir1)
  size_t oP1  = alloc((size_t)NO1 * T_LEN * 4);        // 6.55 MB
  size_t oS1P = alloc((size_t)NO1 * NWORDS * 4);       // 205 KB
  size_t oP2  = alloc((size_t)T_LEN * 4);              // 262 KB
  size_t oWG3 = alloc((size_t)2 * NCH * 16 * 4);       // 32 KB
  if (ws_size < off) {
    k_fill<<<T_LEN / 256, 256, 0, stream>>>(out, 2.0f);
    return;
  }

  float*    y1   = (float*)(ws + oY1);
  float*    pot1 = (float*)(ws + oP1);
  unsigned* s1p  = (unsigned*)(ws + oS1P);
  float*    pot2 = (float*)(ws + oP2);
  float*    wg3  = (float*)(ws + oWG3);
  // spec buffers alias the y1 region (dead once k_fir1 completes; spec
  // kernels launch after k_fir1 in stream order). Offsets 256-aligned.
  char* yb = ws + oY1;
  unsigned* si1 = (unsigned*)(yb);                  // 25*1024*4 = 102400 B
  unsigned* so1 = (unsigned*)(yb + 102400);         // 102400 B
  float*    sb1 = (float*)   (yb + 204800);         // 25*1024*64 = 1638400 B
  unsigned* si2 = (unsigned*)(yb + 1843200);        // 4096 B
  unsigned* so2 = (unsigned*)(yb + 1847296);        // 4096 B
  float*    sb2 = (float*)   (yb + 1851392);        // 65536 B

  k_prep4<<<1, 256, 0, stream>>>(w1, wg3);
  k_mm1<<<T_LEN / TT, 1024, 0, stream>>>(x, wg3, y1);
  k_fir1<<<dim3(T_LEN / FTILE, NO1), 256, 0, stream>>>(y1, srm, pot1);
  k_scan_spec<NO1, true><<<(NO1 * NBK + 63) / 64, 64, 0, stream>>>(
      pot1, refk, nullptr, s1p, si1, so1, sb1);
  k_scan_fix<NO1, true><<<NO1, 64, 0, stream>>>(pot1, refk, nullptr, s1p, si1, so1, sb1);
  k_pot2<<<T_LEN / FT2, 256, 0, stream>>>(s1p, srm, w2, pot2);
  k_scan_spec<1, false><<<(NBK + 63) / 64, 64, 0, stream>>>(
      pot2, refk, out, nullptr, si2, so2, sb2);
  k_scan_fix<1, false><<<1, 64, 0, stream>>>(pot2, refk, out, nullptr, si2, so2, sb2);
}

// Round 23
// 85.820 us; speedup vs baseline: 1.1306x; 1.0807x over previous
//
#include <hip/hip_runtime.h>

// SlayerNet SNN forward, MI355X. (R18 configuration — session best, 87.3us.)
// y1 = w1@x [k_mm1: 8 waves = 4 o-groups x 2 c-halves, float2/lane, acc[7]x2,
//   padded 8-float weight rows (1 s_load_dwordx8/ch), unroll 10, LDS fold] ;
// pot1 = FIR129(y1) [k_fir1] ; s1 = scan [bits] ;
// pot2 = FIR129(w2@s1) [linearity swap, b128 FIR] ; s2 = scan -> d_out (fp32).
// Spike scans: speculative block-parallel + exact fixup (state = last 15 spike
// bits; 15-bit mask match => bitwise-exact). LBLK=64 minimizes per-thread
// serial chain (scans are latency-bound, not throughput-bound).

#define T_LEN   65536
#define NCH     250
#define NO1     25
#define KTAPS   129      // taps d=0..128, eps[d] = srm[128-d]
#define PAD     128
#define SRM_LEN 257
#define REF_LEN 16
#define THETA_F 10.0f
#define LBLK    64       // scan block length (== 2 x 32-bit words)
#define NBK     1024     // NBK*LBLK == T_LEN
#define WARM    64       // speculative warm-up steps
#define TT      128      // mm1 time-tile (2 positions per lane)
#define FTILE   1024     // fir1 tile
#define FT2     1024     // pot2 tile
#define NWORDS  (T_LEN / 32)
#define CHALF   125      // channels per half

// One gen_spikes step. fma(s,rn,b) is bit-exact vs fadd(b,fmul(s,rn)):
// s in {0,1} makes the product exact, so single rounding = same rounding.
__device__ __forceinline__ void srm_step(float p, const float (&rn)[15], float (&b)[15],
                                         unsigned &m, float &sf_out) {
  float u = p + b[0];
  unsigned sp = (u >= THETA_F) ? 1u : 0u;
  float sf = sp ? 1.0f : 0.0f;
#pragma unroll
  for (int j = 0; j < 14; ++j) b[j] = __builtin_fmaf(sf, rn[j], b[j + 1]);
  b[14] = __fmul_rn(sf, rn[14]);
  m = (m << 1) | sp;
  sf_out = sf;
}

__global__ void k_fill(float* out, float v) {
  out[blockIdx.x * 256 + threadIdx.x] = v;
}

// Padded per-group weights: wg2[og][c][j] = w1[og*6+j][c] (j < no(og)) else 0.
__global__ __launch_bounds__(256) void k_prep3(const float* __restrict__ w1,
                                               float* __restrict__ wg2) {
  for (int i = threadIdx.x; i < 4 * NCH * 8; i += 256) {
    int og = i / (NCH * 8);
    int r = i - og * (NCH * 8);
    int c = r >> 3;
    int j = r & 7;
    int ob = og * 6;
    int no = (og == 3) ? 7 : 6;
    wg2[i] = (j < no) ? w1[(ob + j) * NCH + c] : 0.0f;
  }
}

// K1: y1[o][t] = sum_{c} w1[o][c]*x[c][t].
// 512 thr = 8 waves: wave w -> o-group (w&3), c-half (w>>2).
// Per wave: 125 channels, float2/lane, acc[7]x2 (14 live VGPR), one aligned
// dwordx8 scalar load per channel, unroll 10 => ~13 stall-points.
// Halves folded via LDS: acc = acc_h0 + acc_h1 (same order as R5, verified).
__global__ __launch_bounds__(512, 8) void k_mm1(const float* __restrict__ x,
                                                const float* __restrict__ wg2,
                                                float* __restrict__ y1) {
  __shared__ __align__(16) float2 part[4][7][64];  // 14336 B
  const int tid = threadIdx.x;
  const int lane = tid & 63;
  const int og = __builtin_amdgcn_readfirstlane((tid >> 6) & 3);
  const int half = __builtin_amdgcn_readfirstlane(tid >> 8);
  const int ob = og * 6;
  const int no = (og == 3) ? 7 : 6;
  const int t = blockIdx.x * TT + lane * 2;
  const float* wp = wg2 + og * (NCH * 8) + half * CHALF * 8;  // SGPR base
  const float* xp = x + (size_t)(half * CHALF) * T_LEN + t;
  float2 acc[7];
#pragma unroll
  for (int j = 0; j < 7; ++j) acc[j] = make_float2(0.f, 0.f);
#pragma unroll 10
  for (int c = 0; c < CHALF; ++c) {
    float2 xv = *(const float2*)(xp + (size_t)c * T_LEN);  // 512B/wave
    const float* wr = wp + c * 8;           // uniform, 32B-aligned -> dwordx8
#pragma unroll
    for (int j = 0; j < 7; ++j) {           // j==6 zero-weight for og<3
      acc[j].x = __builtin_fmaf(wr[j], xv.x, acc[j].x);
      acc[j].y = __builtin_fmaf(wr[j], xv.y, acc[j].y);
    }
  }
  if (half == 1) {
#pragma unroll
    for (int j = 0; j < 7; ++j) part[og][j][lane] = acc[j];
  }
  __syncthreads();
  if (half == 0) {
#pragma unroll
    for (int j = 0; j < 7; ++j) {
      float2 p = part[og][j][lane];
      acc[j].x = __fadd_rn(acc[j].x, p.x);   // h0 + h1 (R5-verified order)
      acc[j].y = __fadd_rn(acc[j].y, p.y);
      if (j < no) *(float2*)&y1[(size_t)(ob + j) * T_LEN + t] = acc[j];
    }
  }
}

// K2: pot1[o][t] = sum_d eps[d]*y1[o][t-d]; plain y1 layout.
__global__ __launch_bounds__(256, 8) void k_fir1(const float* __restrict__ y1,
                                                 const float* __restrict__ srm,
                                                 float* __restrict__ pot1) {
  __shared__ __align__(16) float win[FTILE + PAD];
  const int tid = threadIdx.x;
  const int o = blockIdx.y;
  const int t0 = blockIdx.x * FTILE;
  const float* yr = y1 + (size_t)o * T_LEN;
  for (int j = tid; j < FTILE + PAD; j += 256) {
    int g = t0 - PAD + j;
    win[j] = (g >= 0) ? yr[g] : 0.0f;
  }
  __syncthreads();
  const int base = tid * 4;
  float q0 = 0.0f, q1 = 0.0f, q2 = 0.0f, q3 = 0.0f;
  // i descending => per-output tap order d ascending (proven ordering).
#pragma unroll
  for (int i = 32; i >= 0; --i) {
    float4 v = *(const float4*)&win[base + 4 * i];
#pragma unroll
    for (int l = 3; l >= 0; --l) {
      float vl = (l == 0) ? v.x : (l == 1) ? v.y : (l == 2) ? v.z : v.w;
#pragma unroll
      for (int k = 0; k < 4; ++k) {
        int d = 128 + k - 4 * i - l;
        if (d >= 0 && d <= 128) {
          float e = srm[4 * i + l - k];  // uniform -> scalar load
          if (k == 0) q0 = __builtin_fmaf(e, vl, q0);
          else if (k == 1) q1 = __builtin_fmaf(e, vl, q1);
          else if (k == 2) q2 = __builtin_fmaf(e, vl, q2);
          else q3 = __builtin_fmaf(e, vl, q3);
        }
      }
    }
  }
  *(float4*)&pot1[(size_t)o * T_LEN + t0 + base] = make_float4(q0, q1, q2, q3);
}

// K5: pot2 = FIR129( z ),  z[t] = sum_o w2[o] * s1[o][t]  (bit-packed s1).
__global__ __launch_bounds__(256) void k_pot2(const unsigned* __restrict__ s1p,
                                              const float* __restrict__ srm,
                                              const float* __restrict__ w2,
                                              float* __restrict__ pot2) {
  __shared__ __align__(16) float zs[FT2 + PAD];
  const int tid = threadIdx.x;
  const int t0 = blockIdx.x * FT2;
  for (int j = tid; j < FT2 + PAD; j += 256) {
    int g = t0 - PAD + j;
    float z = 0.0f;
    if (g >= 0) {
      int wi = g >> 5, sh = g & 31;
#pragma unroll
      for (int o = 0; o < NO1; ++o) {
        unsigned wvv = s1p[o * NWORDS + wi];
        z += ((wvv >> sh) & 1u) ? w2[o] : 0.0f;  // w2: uniform scalar load
      }
    }
    zs[j] = z;
  }
  __syncthreads();
  const int base = tid * 4;
  float q0 = 0.0f, q1 = 0.0f, q2 = 0.0f, q3 = 0.0f;
#pragma unroll
  for (int i = 32; i >= 0; --i) {
    float4 v = *(const float4*)&zs[base + 4 * i];
#pragma unroll
    for (int l = 3; l >= 0; --l) {
      float vl = (l == 0) ? v.x : (l == 1) ? v.y : (l == 2) ? v.z : v.w;
#pragma unroll
      for (int k = 0; k < 4; ++k) {
        int d = 128 + k - 4 * i - l;
        if (d >= 0 && d <= 128) {
          float e = srm[4 * i + l - k];
          if (k == 0) q0 = __builtin_fmaf(e, vl, q0);
          else if (k == 1) q1 = __builtin_fmaf(e, vl, q1);
          else if (k == 2) q2 = __builtin_fmaf(e, vl, q2);
          else q3 = __builtin_fmaf(e, vl, q3);
        }
      }
    }
  }
  *(float4*)&pot2[t0 + base] = make_float4(q0, q1, q2, q3);
}

// Speculative scan: one thread per (channel, block). WARM steps from assumed
// zero state, then LBLK emitted steps; 4-deep float4 prefetch (16 steps/iter).
template <int C, bool PACKED>
__global__ __launch_bounds__(64) void k_scan_spec(const float* __restrict__ pot,
                                                  const float* __restrict__ refk,
                                                  float* __restrict__ s,
                                                  unsigned* __restrict__ sp_,
                                                  unsigned* __restrict__ specin_m,
                                                  unsigned* __restrict__ specout_m,
                                                  float* __restrict__ specout_b) {
  int idx = blockIdx.x * 64 + threadIdx.x;
  if (idx >= C * NBK) return;
  int c = idx / NBK;
  int bb = idx - c * NBK;
  int tsr = bb * LBLK - WARM;
  float rn[15];
#pragma unroll
  for (int j = 0; j < 15; ++j) rn[j] = refk[j + 1];
  float b[15];
#pragma unroll
  for (int j = 0; j < 15; ++j) b[j] = 0.0f;
  unsigned m = 0;
  const float* prow = pot + (size_t)c * T_LEN;
  float* srow = PACKED ? nullptr : (s + (size_t)c * T_LEN);
  unsigned* srowp = PACKED ? (sp_ + (size_t)c * NWORDS) : nullptr;

  auto proc4 = [&](float4 pv, int tg, bool emit) {
    float s0, s1v, s2, s3;
    srm_step(pv.x, rn, b, m, s0);
    srm_step(pv.y, rn, b, m, s1v);
    srm_step(pv.z, rn, b, m, s2);
    srm_step(pv.w, rn, b, m, s3);
    if (emit) {
      if (PACKED) {
        if (((tg + 3) & 31) == 31) srowp[(tg - 28) >> 5] = __brev(m);
      } else {
        *(float4*)(srow + tg) = make_float4(s0, s1v, s2, s3);
      }
    }
  };

  for (int k = 0; k < WARM + LBLK; k += 16) {
    if (k == WARM) specin_m[idx] = m & 0x7FFFu;
    int t = tsr + k;
    if (t < 0) continue;   // t is a multiple of 16; never partially negative
    float4 p0 = *(const float4*)(prow + t);
    float4 p1 = *(const float4*)(prow + t + 4);
    float4 p2 = *(const float4*)(prow + t + 8);
    float4 p3 = *(const float4*)(prow + t + 12);
    const bool emit = (k >= WARM);
    proc4(p0, t, emit);
    proc4(p1, t + 4, emit);
    proc4(p2, t + 8, emit);
    proc4(p3, t + 12, emit);
  }
  specout_m[idx] = m & 0x7FFFu;
#pragma unroll
  for (int j = 0; j < 15; ++j) specout_b[idx * 16 + j] = b[j];
}

// Exact fixup: one WAVE per channel. All 16 mask-groups preloaded, ballot
// chain check => 64 blocks/iter fast path; mismatch path walks via shuffles.
template <int C, bool PACKED>
__global__ __launch_bounds__(64) void k_scan_fix(const float* __restrict__ pot,
                                                 const float* __restrict__ refk,
                                                 float* __restrict__ s,
                                                 unsigned* __restrict__ sp_,
                                                 const unsigned* __restrict__ specin_m,
                                                 const unsigned* __restrict__ specout_m,
                                                 const float* __restrict__ specout_b) {
  const int c = blockIdx.x;
  const int lane = threadIdx.x;
  float rn[15];
#pragma unroll
  for (int j = 0; j < 15; ++j) rn[j] = refk[j + 1];
  float b[15];
#pragma unroll
  for (int j = 0; j < 15; ++j) b[j] = 0.0f;
  unsigned m = 0;
  bool haveB = true;
  const float* prow = pot + (size_t)c * T_LEN;
  float* srow = PACKED ? nullptr : (s + (size_t)c * T_LEN);
  unsigned* srowp = PACKED ? (sp_ + (size_t)c * NWORDS) : nullptr;
  unsigned prev_last = 0;

  unsigned siv[NBK / 64], sov[NBK / 64];
#pragma unroll
  for (int g = 0; g < NBK / 64; ++g) {
    siv[g] = specin_m[c * NBK + g * 64 + lane];
    sov[g] = specout_m[c * NBK + g * 64 + lane];
  }
#pragma unroll
  for (int g = 0; g < NBK / 64; ++g) {
    const unsigned si = siv[g];
    const unsigned so = sov[g];
    unsigned so_prev = __shfl_up(so, 1);
    if (lane == 0) so_prev = prev_last;
    const unsigned long long flags = __ballot(si == so_prev);
    prev_last = __shfl(so, 63);
    const unsigned si0 = __shfl(si, 0);
    if (flags == ~0ull && (m & 0x7FFFu) == si0) {
      m = prev_last;
      haveB = false;
      continue;
    }
    for (int r = 0; r < 64; ++r) {
      const unsigned sir = __shfl(si, r);
      const unsigned sor = __shfl(so, r);
      if ((m & 0x7FFFu) == sir) {
        m = sor;
        haveB = false;
      } else {
        const int bbr = g * 64 + r;  // bbr>=1: block 0 entry mask 0 always matches
        if (!haveB) {
          const int pb = (c * NBK + bbr - 1) * 16;
#pragma unroll
          for (int q2 = 0; q2 < 15; ++q2) b[q2] = specout_b[pb + q2];
          haveB = true;
        }
        const int t0 = bbr * LBLK;
        for (int t = t0; t < t0 + LBLK; t += 4) {
          float4 pv = *(const float4*)(prow + t);
          float s0, s1v, s2, s3;
          srm_step(pv.x, rn, b, m, s0);
          srm_step(pv.y, rn, b, m, s1v);
          srm_step(pv.z, rn, b, m, s2);
          srm_step(pv.w, rn, b, m, s3);
          if (PACKED) {
            if ((((t + 3) & 31) == 31) && lane == 0) srowp[(t - 28) >> 5] = __brev(m);
          } else {
            if (lane == 0) *(float4*)(srow + t) = make_float4(s0, s1v, s2, s3);
          }
        }
        haveB = true;
      }
    }
  }
}

extern "C" void kernel_launch(void* const* d_in, const int* in_sizes, int n_in,
                              void* d_out, int out_size, void* d_ws, size_t ws_size,
                              hipStream_t stream) {
  const float* x    = (const float*)d_in[0];  // 250*65536
  const float* srm  = (const float*)d_in[1];  // 257
  const float* refk = (const float*)d_in[2];  // 16
  const float* w1   = (const float*)d_in[3];  // 25*250
  const float* w2   = (const float*)d_in[4];  // 25
  float* out = (float*)d_out;

  float bad = 0.0f;
  if (n_in != 5) bad = 3.0f;
  else if (in_sizes[0] != NCH * T_LEN) bad = 4.0f;
  else if (in_sizes[1] != SRM_LEN)     bad = 5.0f;
  else if (in_sizes[2] != REF_LEN)     bad = 6.0f;
  else if (in_sizes[3] != NO1 * NCH)   bad = 7.0f;
  else if (in_sizes[4] != NO1)         bad = 8.0f;
  else if (out_size != T_LEN)          bad = 9.0f;
  if (bad != 0.0f) {
    k_fill<<<T_LEN / 256, 256, 0, stream>>>(out, bad);
    return;
  }

  size_t off = 0;
  auto alloc = [&](size_t bytes) { size_t o = off; off = (off + bytes + 255) & ~(size_t)255; return o; };
  char* ws = (char*)d_ws;
  size_t oY1  = alloc((size_t)NO1 * T_LEN * 4);        // 6.55 MB (dead after k_fir1)
  size_t oP1  = alloc((size_t)NO1 * T_LEN * 4);        // 6.55 MB
  size_t oS1P = alloc((size_t)NO1 * NWORDS * 4);       // 205 KB
  size_t oP2  = alloc((size_t)T_LEN * 4);              // 262 KB
  size_t oWG2 = alloc((size_t)4 * NCH * 8 * 4);        // 32 KB
  if (ws_size < off) {
    k_fill<<<T_LEN / 256, 256, 0, stream>>>(out, 2.0f);
    return;
  }

  float*    y1   = (float*)(ws + oY1);
  float*    pot1 = (float*)(ws + oP1);
  unsigned* s1p  = (unsigned*)(ws + oS1P);
  float*    pot2 = (float*)(ws + oP2);
  float*    wg2  = (float*)(ws + oWG2);
  // spec buffers alias the y1 region (dead once k_fir1 completes; spec
  // kernels launch after k_fir1 in stream order). Offsets 256-aligned.
  char* yb = ws + oY1;
  unsigned* si1 = (unsigned*)(yb);                  // 25*1024*4 = 102400 B
  unsigned* so1 = (unsigned*)(yb + 102400);         // 102400 B
  float*    sb1 = (float*)   (yb + 204800);         // 25*1024*64 = 1638400 B
  unsigned* si2 = (unsigned*)(yb + 1843200);        // 4096 B
  unsigned* so2 = (unsigned*)(yb + 1847296);        // 4096 B
  float*    sb2 = (float*)   (yb + 1851392);        // 65536 B

  k_prep3<<<1, 256, 0, stream>>>(w1, wg2);
  k_mm1<<<T_LEN / TT, 512, 0, stream>>>(x, wg2, y1);
  k_fir1<<<dim3(T_LEN / FTILE, NO1), 256, 0, stream>>>(y1, srm, pot1);
  k_scan_spec<NO1, true><<<(NO1 * NBK + 63) / 64, 64, 0, stream>>>(
      pot1, refk, nullptr, s1p, si1, so1, sb1);
  k_scan_fix<NO1, true><<<NO1, 64, 0, stream>>>(pot1, refk, nullptr, s1p, si1, so1, sb1);
  k_pot2<<<T_LEN / FT2, 256, 0, stream>>>(s1p, srm, w2, pot2);
  k_scan_spec<1, false><<<(NBK + 63) / 64, 64, 0, stream>>>(
      pot2, refk, out, nullptr, si2, so2, sb2);
  k_scan_fix<1, false><<<1, 64, 0, stream>>>(pot2, refk, out, nullptr, si2, so2, sb2);
}